// Round 4
// baseline (418.940 us; speedup 1.0000x reference)
//
#include <hip/hip_runtime.h>

#define B_ 16
#define L_ 4096
#define H_ 128
#define DM 11
#define LB 8
#define T_ (L_-LB)            /* 4088 */
#define TT 64                 /* t per block, 1 per lane of each wave */
#define NTB (L_/TT)           /* 64 tiles */
#define NBLK (NTB*B_)         /* 1024 blocks */
#define EPSC 1e-6f
#define MAGS_BASE 4096
#define QONLY_BASE 8192

/* ws layout (floats):
   [0..3071]       attn |delta| partials, 3 variants x 1024 blocks
   [4096..6143]    mags partials, 1024 blocks x {vec,biv}
   [8192..8239]    qonly |delta|, 16 b x 3 variants
*/

/* wave-private stage->score sync: all prior LDS ops complete, no compiler motion */
#define WAVE_SYNC() do { asm volatile("s_waitcnt lgkmcnt(0)" ::: "memory"); \
                         __builtin_amdgcn_sched_barrier(0); } while (0)

__device__ __forceinline__ float phi_f(float a) { return fmaxf(a, 0.01f * a) + 1.f; }

__device__ __forceinline__ float4 phi4(float a, float b, float c, float d) {
  return make_float4(phi_f(a), phi_f(b), phi_f(c), phi_f(d));
}

/* r[0..3] = vector dims (M dims 1..4), r[4..9] = bivector dims (M dims 5..10) */
__device__ __forceinline__ void ga_parts(const float4 xv, const float* __restrict__ vs4,
                                         const float* __restrict__ vb4,
                                         const float* __restrict__ bw6, float* __restrict__ r) {
  r[0] = xv.x * vs4[0] + vb4[0];
  r[1] = xv.y * vs4[1] + vb4[1];
  r[2] = xv.z * vs4[2] + vb4[2];
  r[3] = xv.w * vs4[3] + vb4[3];
  r[4] = bw6[0] * (xv.x - xv.y);
  r[5] = bw6[1] * (xv.x - xv.z);
  r[6] = bw6[2] * (xv.x - xv.w);
  r[7] = bw6[3] * (xv.y - xv.z);
  r[8] = bw6[4] * (xv.y - xv.w);
  r[9] = bw6[5] * (xv.z - xv.w);
}

/* vec & biv partial dots against an 11-float weight row (w[0]=scalar, w[1..10]) */
__device__ __forceinline__ void dot2(const float* __restrict__ r, const float* __restrict__ w,
                                     float& dv, float& db) {
  dv = r[0] * w[1] + r[1] * w[2] + r[2] * w[3] + r[3] * w[4];
  db = r[4] * w[5] + r[5] * w[6] + r[6] * w[7] + r[7] * w[8] + r[8] * w[9] + r[9] * w[10];
}

__global__ __launch_bounds__(256, 4) void attn_kernel(
    const float* __restrict__ x, const float* __restrict__ sbp,
    const float* __restrict__ vs, const float* __restrict__ vb,
    const float* __restrict__ bw, const float* __restrict__ WQ,
    const float* __restrict__ WK, const float* __restrict__ WV,
    const float* __restrict__ hW, const float* __restrict__ hb,
    float* __restrict__ out, float* __restrict__ ws)
{
  __shared__ float4 sK4[4][8][72];   /* [wave][hl][row] — h-major, conflict-free */
  __shared__ float4 sU4[72];
  __shared__ float  sWVe[16];

  const int tid  = threadIdx.x;
  const int lane = tid & 63;
  const int hq   = __builtin_amdgcn_readfirstlane(tid >> 6);  /* wave = h-quarter */
  const int tile = blockIdx.x;
  const int b    = blockIdx.y;
  const int base = tile * TT;

  const float sb0 = sbp[0];
  const float m0c = 1.f + sb0;
  float vs4[4] = {vs[0], vs[1], vs[2], vs[3]};
  float vb4[4] = {vb[0], vb[1], vb[2], vb[3]};
  float bw6[6] = {bw[0], bw[1], bw[2], bw[3], bw[4], bw[5]};
  const float hb0 = hb[0];

  const float4* xb = (const float4*)x + (size_t)b * L_;

  /* M rows in registers: staging row (lane), q row (lane+8), extra rows 64..71 (lanes 0..7) */
  float ms[10], mq[10], m2[10];
  ga_parts(xb[base + lane], vs4, vb4, bw6, ms);
  {
    int qp = base + lane + LB;
    if (qp < L_) ga_parts(xb[qp], vs4, vb4, bw6, mq);
    else { for (int i = 0; i < 10; ++i) mq[i] = 0.f; }
  }
  const bool has2 = (lane < LB);
  if (has2) {
    int p2 = base + 64 + lane;
    if (p2 < L_) ga_parts(xb[p2], vs4, vb4, bw6, m2);
    else { for (int i = 0; i < 10; ++i) m2[i] = 0.f; }
  }
  float magv = fabsf(ms[0]) + fabsf(ms[1]) + fabsf(ms[2]) + fabsf(ms[3]);
  float magb = fabsf(ms[4]) + fabsf(ms[5]) + fabsf(ms[6]) + fabsf(ms[7]) + fabsf(ms[8]) + fabsf(ms[9]);

  /* WVe by wave 1 */
  if (hq == 1 && lane < DM) {
    float a = 0.f;
    for (int g = 0; g < H_; ++g) a += WV[g * DM + lane] * hW[g];
    sWVe[lane] = a;
  }
  __syncthreads();   /* #1: sWVe ready */

  /* wave 0 stages u4 (variant-packed u = M . WVe) */
  if (hq == 0) {
    float wv[11];
#pragma unroll
    for (int d = 0; d < DM; ++d) wv[d] = sWVe[d];
    float dv, db;
    dot2(ms, wv, dv, db);
    float c0 = m0c * wv[0];
    sU4[lane] = make_float4(c0 + dv + db, dv + db, c0 + db, c0 + dv);
    if (has2) {
      dot2(m2, wv, dv, db);
      sU4[64 + lane] = make_float4(c0 + dv + db, dv + db, c0 + db, c0 + dv);
    }
  }

  float4 s4[8];
#pragma unroll
  for (int l = 0; l < 8; ++l) s4[l] = make_float4(0.f, 0.f, 0.f, 0.f);

  const float* __restrict__ WKq = WK + (hq * 32) * DM;  /* uniform base */
  const float* __restrict__ WQq = WQ + (hq * 32) * DM;

#pragma unroll
  for (int c = 0; c < 4; ++c) {           /* 4 chunks of 8 h per wave */
#pragma unroll
    for (int hl = 0; hl < 8; ++hl) {
      const float* wk = WKq + (c * 8 + hl) * DM;   /* uniform -> s_load */
      float dv, db;
      dot2(ms, wk, dv, db);
      float c0 = m0c * wk[0];
      float t1 = dv + db;
      sK4[hq][hl][lane] = phi4(c0 + t1, t1, c0 + db, c0 + dv);
    }
    if (has2) {
#pragma unroll
      for (int hl = 0; hl < 8; ++hl) {
        const float* wk = WKq + (c * 8 + hl) * DM;
        float dv, db;
        dot2(m2, wk, dv, db);
        float c0 = m0c * wk[0];
        float t1 = dv + db;
        sK4[hq][hl][64 + lane] = phi4(c0 + t1, t1, c0 + db, c0 + dv);
      }
    }
    WAVE_SYNC();
#pragma unroll
    for (int hl = 0; hl < 8; ++hl) {
      const float* wq = WQq + (c * 8 + hl) * DM;   /* uniform -> s_load */
      float dv, db;
      dot2(mq, wq, dv, db);
      float c0 = m0c * wq[0];
      float t1 = dv + db;
      float4 q4 = phi4(c0 + t1, t1, c0 + db, c0 + dv);
#pragma unroll
      for (int l = 0; l < 8; ++l) {
        float4 k4 = sK4[hq][hl][lane + l];
        s4[l].x += q4.x * k4.x;
        s4[l].y += q4.y * k4.y;
        s4[l].z += q4.z * k4.z;
        s4[l].w += q4.w * k4.w;
      }
    }
    WAVE_SYNC();
  }

  /* cross-wave score reduce: reuse sK4 as scratch (swizzled slots) */
  __syncthreads();   /* #2: scoring done everywhere */
  float4* scr = &sK4[0][0][0];
  if (hq != 0) {
    int off = (hq - 1) * 512 + lane * 8;
#pragma unroll
    for (int l = 0; l < 8; ++l) scr[off + (l ^ (lane & 7))] = s4[l];
  }
  __syncthreads();   /* #3 */

  if (hq == 0) {
#pragma unroll
    for (int j = 0; j < 3; ++j) {
      int off = j * 512 + lane * 8;
#pragma unroll
      for (int l = 0; l < 8; ++l) {
        float4 v = scr[off + (l ^ (lane & 7))];
        s4[l].x += v.x; s4[l].y += v.y; s4[l].z += v.z; s4[l].w += v.w;
      }
    }
    float den0 = EPSC, den1 = EPSC, den2 = EPSC, den3 = EPSC;
    float num0 = 0.f, num1 = 0.f, num2 = 0.f, num3 = 0.f;
#pragma unroll
    for (int l = 0; l < 8; ++l) {
      float4 u4 = sU4[lane + l];
      den0 += s4[l].x; num0 += s4[l].x * u4.x;
      den1 += s4[l].y; num1 += s4[l].y * u4.y;
      den2 += s4[l].z; num2 += s4[l].z * u4.z;
      den3 += s4[l].w; num3 += s4[l].w * u4.w;
    }
    float p0 = hb0 + num0 / den0;
    float p1 = hb0 + num1 / den1;
    float p2 = hb0 + num2 / den2;
    float p3 = hb0 + num3 / den3;

    const int t = base + lane;
    const bool tvalid = (t < T_);
    if (tvalid) {
      out[(size_t)b * T_ + t] = p0;
      float inv = 1.f / den0;
      float4* wp = (float4*)(out + (size_t)B_ * T_ + ((size_t)b * T_ + t) * 8);
      wp[0] = make_float4(s4[0].x * inv, s4[1].x * inv, s4[2].x * inv, s4[3].x * inv);
      wp[1] = make_float4(s4[4].x * inv, s4[5].x * inv, s4[6].x * inv, s4[7].x * inv);
    }
    float d1 = tvalid ? fabsf(p0 - p1) : 0.f;
    float d2 = tvalid ? fabsf(p0 - p2) : 0.f;
    float d3 = tvalid ? fabsf(p0 - p3) : 0.f;
#pragma unroll
    for (int off = 32; off >= 1; off >>= 1) {
      d1 += __shfl_xor(d1, off);
      d2 += __shfl_xor(d2, off);
      d3 += __shfl_xor(d3, off);
      magv += __shfl_xor(magv, off);
      magb += __shfl_xor(magb, off);
    }
    if (lane == 0) {
      int bid = b * NTB + tile;
      ws[bid]             = d1;
      ws[1024 + bid]      = d2;
      ws[2048 + bid]      = d3;
      ws[MAGS_BASE + 2 * bid]     = magv;
      ws[MAGS_BASE + 2 * bid + 1] = magb;
    }
  }

  /* qonly fused on wave 1 of the last tile (runs concurrent with wave 0 epilogue) */
  if (hq == 1 && tile == NTB - 1) {
    const int h0 = lane, h1 = lane + 64;
    float wq0[11], wq1[11], wk0[11], wk1[11], wv[11];
#pragma unroll
    for (int d = 0; d < DM; ++d) {
      wq0[d] = WQ[h0 * DM + d]; wq1[d] = WQ[h1 * DM + d];
      wk0[d] = WK[h0 * DM + d]; wk1[d] = WK[h1 * DM + d];
      wv[d]  = sWVe[d];
    }
    float A0 = 0.f, Z0 = 0.f, A1 = 0.f, Z1 = 0.f;
#pragma unroll
    for (int l = 0; l < LB; ++l) {
      float4 xv = xb[L_ - 1 - LB + l];
      float r[10];
      ga_parts(xv, vs4, vb4, bw6, r);
      float uv, ub;
      dot2(r, wv, uv, ub);
      float u = m0c * wv[0] + uv + ub;
      float dv, db;
      dot2(r, wk0, dv, db);
      float k0 = phi_f(m0c * wk0[0] + dv + db);
      dot2(r, wk1, dv, db);
      float k1 = phi_f(m0c * wk1[0] + dv + db);
      A0 += k0 * u; Z0 += k0;
      A1 += k1 * u; Z1 += k1;
    }
    float q0, q1;
    {
      float4 xv = xb[L_ - 1];
      float r[10];
      ga_parts(xv, vs4, vb4, bw6, r);
      float dv, db;
      dot2(r, wq0, dv, db);
      q0 = phi_f(m0c * wq0[0] + dv + db);
      dot2(r, wq1, dv, db);
      q1 = phi_f(m0c * wq1[0] + dv + db);
    }
    float i00 = fabsf(wq0[0]);
    float i01 = fabsf(wq0[1]) + fabsf(wq0[2]) + fabsf(wq0[3]) + fabsf(wq0[4]);
    float i02 = fabsf(wq0[5]) + fabsf(wq0[6]) + fabsf(wq0[7]) + fabsf(wq0[8]) + fabsf(wq0[9]) + fabsf(wq0[10]);
    float i10 = fabsf(wq1[0]);
    float i11 = fabsf(wq1[1]) + fabsf(wq1[2]) + fabsf(wq1[3]) + fabsf(wq1[4]);
    float i12 = fabsf(wq1[5]) + fabsf(wq1[6]) + fabsf(wq1[7]) + fabsf(wq1[8]) + fabsf(wq1[9]) + fabsf(wq1[10]);
    float mm0 = fmaxf(i00, i10), mm1 = fmaxf(i01, i11), mm2 = fmaxf(i02, i12);
#pragma unroll
    for (int off = 32; off >= 1; off >>= 1) {
      mm0 = fmaxf(mm0, __shfl_xor(mm0, off));
      mm1 = fmaxf(mm1, __shfl_xor(mm1, off));
      mm2 = fmaxf(mm2, __shfl_xor(mm2, off));
    }
    mm0 += 1e-12f; mm1 += 1e-12f; mm2 += 1e-12f;
    float qa[4], qb_[4];
    qa[0] = q0;                      qb_[0] = q1;
    qa[1] = q0 * (1.f - i00 / mm0);  qb_[1] = q1 * (1.f - i10 / mm0);
    qa[2] = q0 * (1.f - i01 / mm1);  qb_[2] = q1 * (1.f - i11 / mm1);
    qa[3] = q0 * (1.f - i02 / mm2);  qb_[3] = q1 * (1.f - i12 / mm2);
    float num[4], den[4];
#pragma unroll
    for (int cc = 0; cc < 4; ++cc) {
      num[cc] = qa[cc] * A0 + qb_[cc] * A1;
      den[cc] = qa[cc] * Z0 + qb_[cc] * Z1;
    }
#pragma unroll
    for (int off = 32; off >= 1; off >>= 1) {
#pragma unroll
      for (int cc = 0; cc < 4; ++cc) {
        num[cc] += __shfl_xor(num[cc], off);
        den[cc] += __shfl_xor(den[cc], off);
      }
    }
    if (lane == 0) {
      float o0 = hb0 + num[0] / (den[0] + EPSC);
      float o1 = hb0 + num[1] / (den[1] + EPSC);
      float o2 = hb0 + num[2] / (den[2] + EPSC);
      float o3 = hb0 + num[3] / (den[3] + EPSC);
      ws[QONLY_BASE + b * 3 + 0] = fabsf(o0 - o1);
      ws[QONLY_BASE + b * 3 + 1] = fabsf(o0 - o2);
      ws[QONLY_BASE + b * 3 + 2] = fabsf(o0 - o3);
    }
  }
}

__global__ __launch_bounds__(64) void finalize_kernel(const float* __restrict__ ws,
                                                      const float* __restrict__ sbp,
                                                      float* __restrict__ out)
{
  int lane = threadIdx.x;
  float s0 = 0.f, s1 = 0.f, s2 = 0.f, mv = 0.f, bv = 0.f;
  for (int i = lane; i < NBLK; i += 64) {
    s0 += ws[i];
    s1 += ws[1024 + i];
    s2 += ws[2048 + i];
    mv += ws[MAGS_BASE + 2 * i];
    bv += ws[MAGS_BASE + 2 * i + 1];
  }
#pragma unroll
  for (int off = 32; off >= 1; off >>= 1) {
    s0 += __shfl_xor(s0, off);
    s1 += __shfl_xor(s1, off);
    s2 += __shfl_xor(s2, off);
    mv += __shfl_xor(mv, off);
    bv += __shfl_xor(bv, off);
  }
  if (lane == 0) {
    float q0 = 0.f, q1 = 0.f, q2 = 0.f;
    for (int b = 0; b < B_; ++b) {
      q0 += ws[QONLY_BASE + b * 3 + 0];
      q1 += ws[QONLY_BASE + b * 3 + 1];
      q2 += ws[QONLY_BASE + b * 3 + 2];
    }
    float* oi = out + (size_t)B_ * T_ + (size_t)B_ * T_ * 8;
    const float inv_bt = 1.f / ((float)B_ * (float)T_);
    oi[0] = fabsf(1.f + sbp[0]);
    oi[1] = mv / ((float)B_ * (float)L_ * 4.f);
    oi[2] = bv / ((float)B_ * (float)L_ * 6.f);
    oi[3] = s0 * inv_bt;
    oi[4] = s1 * inv_bt;
    oi[5] = s2 * inv_bt;
    oi[6] = q0 / (float)B_;
    oi[7] = q1 / (float)B_;
    oi[8] = q2 / (float)B_;
  }
}

extern "C" void kernel_launch(void* const* d_in, const int* in_sizes, int n_in,
                              void* d_out, int out_size, void* d_ws, size_t ws_size,
                              hipStream_t stream) {
  (void)in_sizes; (void)n_in; (void)out_size; (void)ws_size;
  const float* x  = (const float*)d_in[0];
  const float* sb = (const float*)d_in[1];
  const float* vs = (const float*)d_in[2];
  const float* vb = (const float*)d_in[3];
  const float* bw = (const float*)d_in[4];
  const float* WQ = (const float*)d_in[5];
  const float* WK = (const float*)d_in[6];
  const float* WV = (const float*)d_in[7];
  const float* hW = (const float*)d_in[8];
  const float* hb = (const float*)d_in[9];
  float* out = (float*)d_out;
  float* ws  = (float*)d_ws;

  attn_kernel<<<dim3(NTB, B_), 256, 0, stream>>>(x, sb, vs, vb, bw, WQ, WK, WV, hW, hb, out, ws);
  finalize_kernel<<<1, 64, 0, stream>>>(ws, sb, out);
}

// Round 5
// 188.702 us; speedup vs baseline: 2.2201x; 2.2201x over previous
//
#include <hip/hip_runtime.h>

#define B_ 16
#define L_ 4096
#define H_ 128
#define DM 11
#define LB 8
#define T_ (L_-LB)            /* 4088 */
#define TT 64                 /* t per block, 1 per lane of each wave */
#define NTB (L_/TT)           /* 64 tiles */
#define NBLK (NTB*B_)         /* 1024 blocks */
#define EPSC 1e-6f
#define MAGS_BASE 4096
#define QONLY_BASE 8192

/* ws layout (floats):
   [0..3071]       attn |delta| partials, 3 variants x 1024 blocks
   [4096..6143]    mags partials, 1024 blocks x {vec,biv}
   [8192..8239]    qonly |delta|, 16 b x 3 variants
*/

__device__ __forceinline__ float phi_f(float a) { return fmaxf(a, 0.01f * a) + 1.f; }

__device__ __forceinline__ float4 phi4(float a, float b, float c, float d) {
  return make_float4(phi_f(a), phi_f(b), phi_f(c), phi_f(d));
}

/* r[0..3] = vector dims (M dims 1..4), r[4..9] = bivector dims (M dims 5..10) */
__device__ __forceinline__ void ga_parts(const float4 xv, const float* __restrict__ vs4,
                                         const float* __restrict__ vb4,
                                         const float* __restrict__ bw6, float* __restrict__ r) {
  r[0] = xv.x * vs4[0] + vb4[0];
  r[1] = xv.y * vs4[1] + vb4[1];
  r[2] = xv.z * vs4[2] + vb4[2];
  r[3] = xv.w * vs4[3] + vb4[3];
  r[4] = bw6[0] * (xv.x - xv.y);
  r[5] = bw6[1] * (xv.x - xv.z);
  r[6] = bw6[2] * (xv.x - xv.w);
  r[7] = bw6[3] * (xv.y - xv.z);
  r[8] = bw6[4] * (xv.y - xv.w);
  r[9] = bw6[5] * (xv.z - xv.w);
}

/* vec & biv partial dots against an 11-float weight row (w[0]=scalar, w[1..10]) */
__device__ __forceinline__ void dot2(const float* __restrict__ r, const float* __restrict__ w,
                                     float& dv, float& db) {
  dv = r[0] * w[1] + r[1] * w[2] + r[2] * w[3] + r[3] * w[4];
  db = r[4] * w[5] + r[5] * w[6] + r[6] * w[7] + r[7] * w[8] + r[8] * w[9] + r[9] * w[10];
}

__global__ __launch_bounds__(256, 3) void attn_kernel(
    const float* __restrict__ x, const float* __restrict__ sbp,
    const float* __restrict__ vs, const float* __restrict__ vb,
    const float* __restrict__ bw, const float* __restrict__ WQ,
    const float* __restrict__ WK, const float* __restrict__ WV,
    const float* __restrict__ hW, const float* __restrict__ hb,
    float* __restrict__ out, float* __restrict__ ws)
{
  __shared__ float4 sK4[4][8][72];   /* [wave][hl][row] — h-major, conflict-free */
  __shared__ float4 sU4[72];
  __shared__ float  sWVe[16];

  const int tid  = threadIdx.x;
  const int lane = tid & 63;
  const int hq   = __builtin_amdgcn_readfirstlane(tid >> 6);  /* wave = h-quarter */
  const int tile = blockIdx.x;
  const int b    = blockIdx.y;
  const int base = tile * TT;

  const float sb0 = sbp[0];
  const float m0c = 1.f + sb0;
  float vs4[4] = {vs[0], vs[1], vs[2], vs[3]};
  float vb4[4] = {vb[0], vb[1], vb[2], vb[3]};
  float bw6[6] = {bw[0], bw[1], bw[2], bw[3], bw[4], bw[5]};
  const float hb0 = hb[0];

  const float4* xb = (const float4*)x + (size_t)b * L_;

  /* M rows in registers: staging row (lane), q row (lane+8), extra rows 64..71 (lanes 0..7) */
  float ms[10], mq[10], m2[10];
  ga_parts(xb[base + lane], vs4, vb4, bw6, ms);
  {
    int qp = base + lane + LB;
    if (qp < L_) ga_parts(xb[qp], vs4, vb4, bw6, mq);
    else { for (int i = 0; i < 10; ++i) mq[i] = 0.f; }
  }
  const bool has2 = (lane < LB);
  if (has2) {
    int p2 = base + 64 + lane;
    if (p2 < L_) ga_parts(xb[p2], vs4, vb4, bw6, m2);
    else { for (int i = 0; i < 10; ++i) m2[i] = 0.f; }
  }
  float magv = fabsf(ms[0]) + fabsf(ms[1]) + fabsf(ms[2]) + fabsf(ms[3]);
  float magb = fabsf(ms[4]) + fabsf(ms[5]) + fabsf(ms[6]) + fabsf(ms[7]) + fabsf(ms[8]) + fabsf(ms[9]);

  /* WVe by wave 1 */
  if (hq == 1 && lane < DM) {
    float a = 0.f;
    for (int g = 0; g < H_; ++g) a += WV[g * DM + lane] * hW[g];
    sWVe[lane] = a;
  }
  __syncthreads();   /* sWVe ready */

  /* wave 0 stages u4 (variant-packed u = M . WVe) */
  if (hq == 0) {
    float wv[11];
#pragma unroll
    for (int d = 0; d < DM; ++d) wv[d] = sWVe[d];
    float dv, db;
    dot2(ms, wv, dv, db);
    float c0 = m0c * wv[0];
    sU4[lane] = make_float4(c0 + dv + db, dv + db, c0 + db, c0 + dv);
    if (has2) {
      dot2(m2, wv, dv, db);
      sU4[64 + lane] = make_float4(c0 + dv + db, dv + db, c0 + db, c0 + dv);
    }
  }

  float4 s4[8];
#pragma unroll
  for (int l = 0; l < 8; ++l) s4[l] = make_float4(0.f, 0.f, 0.f, 0.f);

  const float* __restrict__ WKq = WK + (hq * 32) * DM;  /* uniform base */
  const float* __restrict__ WQq = WQ + (hq * 32) * DM;

#pragma unroll 1
  for (int c = 0; c < 4; ++c) {           /* 4 chunks of 8 h per wave */
#pragma unroll
    for (int hl = 0; hl < 8; ++hl) {
      const float* wk = WKq + (c * 8 + hl) * DM;   /* uniform -> s_load */
      float dv, db;
      dot2(ms, wk, dv, db);
      float c0 = m0c * wk[0];
      float t1 = dv + db;
      sK4[hq][hl][lane] = phi4(c0 + t1, t1, c0 + db, c0 + dv);
    }
    if (has2) {
#pragma unroll
      for (int hl = 0; hl < 8; ++hl) {
        const float* wk = WKq + (c * 8 + hl) * DM;
        float dv, db;
        dot2(m2, wk, dv, db);
        float c0 = m0c * wk[0];
        float t1 = dv + db;
        sK4[hq][hl][64 + lane] = phi4(c0 + t1, t1, c0 + db, c0 + dv);
      }
    }
    __syncthreads();
#pragma unroll
    for (int hl = 0; hl < 8; ++hl) {
      const float* wq = WQq + (c * 8 + hl) * DM;   /* uniform -> s_load */
      float dv, db;
      dot2(mq, wq, dv, db);
      float c0 = m0c * wq[0];
      float t1 = dv + db;
      float4 q4 = phi4(c0 + t1, t1, c0 + db, c0 + dv);
#pragma unroll
      for (int l = 0; l < 8; ++l) {
        float4 k4 = sK4[hq][hl][lane + l];
        s4[l].x += q4.x * k4.x;
        s4[l].y += q4.y * k4.y;
        s4[l].z += q4.z * k4.z;
        s4[l].w += q4.w * k4.w;
      }
    }
    __syncthreads();
  }

  /* cross-wave score reduce: reuse sK4 as scratch (swizzled slots) */
  float4* scr = &sK4[0][0][0];
  if (hq != 0) {
    int off = (hq - 1) * 512 + lane * 8;
#pragma unroll
    for (int l = 0; l < 8; ++l) scr[off + (l ^ (lane & 7))] = s4[l];
  }
  __syncthreads();

  if (hq == 0) {
#pragma unroll
    for (int j = 0; j < 3; ++j) {
      int off = j * 512 + lane * 8;
#pragma unroll
      for (int l = 0; l < 8; ++l) {
        float4 v = scr[off + (l ^ (lane & 7))];
        s4[l].x += v.x; s4[l].y += v.y; s4[l].z += v.z; s4[l].w += v.w;
      }
    }
    float den0 = EPSC, den1 = EPSC, den2 = EPSC, den3 = EPSC;
    float num0 = 0.f, num1 = 0.f, num2 = 0.f, num3 = 0.f;
#pragma unroll
    for (int l = 0; l < 8; ++l) {
      float4 u4 = sU4[lane + l];
      den0 += s4[l].x; num0 += s4[l].x * u4.x;
      den1 += s4[l].y; num1 += s4[l].y * u4.y;
      den2 += s4[l].z; num2 += s4[l].z * u4.z;
      den3 += s4[l].w; num3 += s4[l].w * u4.w;
    }
    float p0 = hb0 + num0 / den0;
    float p1 = hb0 + num1 / den1;
    float p2 = hb0 + num2 / den2;
    float p3 = hb0 + num3 / den3;

    const int t = base + lane;
    const bool tvalid = (t < T_);
    if (tvalid) {
      out[(size_t)b * T_ + t] = p0;
      float inv = 1.f / den0;
      float4* wp = (float4*)(out + (size_t)B_ * T_ + ((size_t)b * T_ + t) * 8);
      wp[0] = make_float4(s4[0].x * inv, s4[1].x * inv, s4[2].x * inv, s4[3].x * inv);
      wp[1] = make_float4(s4[4].x * inv, s4[5].x * inv, s4[6].x * inv, s4[7].x * inv);
    }
    float d1 = tvalid ? fabsf(p0 - p1) : 0.f;
    float d2 = tvalid ? fabsf(p0 - p2) : 0.f;
    float d3 = tvalid ? fabsf(p0 - p3) : 0.f;
#pragma unroll
    for (int off = 32; off >= 1; off >>= 1) {
      d1 += __shfl_xor(d1, off);
      d2 += __shfl_xor(d2, off);
      d3 += __shfl_xor(d3, off);
      magv += __shfl_xor(magv, off);
      magb += __shfl_xor(magb, off);
    }
    if (lane == 0) {
      int bid = b * NTB + tile;
      ws[bid]             = d1;
      ws[1024 + bid]      = d2;
      ws[2048 + bid]      = d3;
      ws[MAGS_BASE + 2 * bid]     = magv;
      ws[MAGS_BASE + 2 * bid + 1] = magb;
    }
  }

  /* qonly fused on wave 1 of the last tile (runs concurrent with wave 0 epilogue) */
  if (hq == 1 && tile == NTB - 1) {
    const int h0 = lane, h1 = lane + 64;
    float wq0[11], wq1[11], wk0[11], wk1[11], wv[11];
#pragma unroll
    for (int d = 0; d < DM; ++d) {
      wq0[d] = WQ[h0 * DM + d]; wq1[d] = WQ[h1 * DM + d];
      wk0[d] = WK[h0 * DM + d]; wk1[d] = WK[h1 * DM + d];
      wv[d]  = sWVe[d];
    }
    float A0 = 0.f, Z0 = 0.f, A1 = 0.f, Z1 = 0.f;
#pragma unroll
    for (int l = 0; l < LB; ++l) {
      float4 xv = xb[L_ - 1 - LB + l];
      float r[10];
      ga_parts(xv, vs4, vb4, bw6, r);
      float uv, ub;
      dot2(r, wv, uv, ub);
      float u = m0c * wv[0] + uv + ub;
      float dv, db;
      dot2(r, wk0, dv, db);
      float k0 = phi_f(m0c * wk0[0] + dv + db);
      dot2(r, wk1, dv, db);
      float k1 = phi_f(m0c * wk1[0] + dv + db);
      A0 += k0 * u; Z0 += k0;
      A1 += k1 * u; Z1 += k1;
    }
    float q0, q1;
    {
      float4 xv = xb[L_ - 1];
      float r[10];
      ga_parts(xv, vs4, vb4, bw6, r);
      float dv, db;
      dot2(r, wq0, dv, db);
      q0 = phi_f(m0c * wq0[0] + dv + db);
      dot2(r, wq1, dv, db);
      q1 = phi_f(m0c * wq1[0] + dv + db);
    }
    float i00 = fabsf(wq0[0]);
    float i01 = fabsf(wq0[1]) + fabsf(wq0[2]) + fabsf(wq0[3]) + fabsf(wq0[4]);
    float i02 = fabsf(wq0[5]) + fabsf(wq0[6]) + fabsf(wq0[7]) + fabsf(wq0[8]) + fabsf(wq0[9]) + fabsf(wq0[10]);
    float i10 = fabsf(wq1[0]);
    float i11 = fabsf(wq1[1]) + fabsf(wq1[2]) + fabsf(wq1[3]) + fabsf(wq1[4]);
    float i12 = fabsf(wq1[5]) + fabsf(wq1[6]) + fabsf(wq1[7]) + fabsf(wq1[8]) + fabsf(wq1[9]) + fabsf(wq1[10]);
    float mm0 = fmaxf(i00, i10), mm1 = fmaxf(i01, i11), mm2 = fmaxf(i02, i12);
#pragma unroll
    for (int off = 32; off >= 1; off >>= 1) {
      mm0 = fmaxf(mm0, __shfl_xor(mm0, off));
      mm1 = fmaxf(mm1, __shfl_xor(mm1, off));
      mm2 = fmaxf(mm2, __shfl_xor(mm2, off));
    }
    mm0 += 1e-12f; mm1 += 1e-12f; mm2 += 1e-12f;
    float qa[4], qb_[4];
    qa[0] = q0;                      qb_[0] = q1;
    qa[1] = q0 * (1.f - i00 / mm0);  qb_[1] = q1 * (1.f - i10 / mm0);
    qa[2] = q0 * (1.f - i01 / mm1);  qb_[2] = q1 * (1.f - i11 / mm1);
    qa[3] = q0 * (1.f - i02 / mm2);  qb_[3] = q1 * (1.f - i12 / mm2);
    float num[4], den[4];
#pragma unroll
    for (int cc = 0; cc < 4; ++cc) {
      num[cc] = qa[cc] * A0 + qb_[cc] * A1;
      den[cc] = qa[cc] * Z0 + qb_[cc] * Z1;
    }
#pragma unroll
    for (int off = 32; off >= 1; off >>= 1) {
#pragma unroll
      for (int cc = 0; cc < 4; ++cc) {
        num[cc] += __shfl_xor(num[cc], off);
        den[cc] += __shfl_xor(den[cc], off);
      }
    }
    if (lane == 0) {
      float o0 = hb0 + num[0] / (den[0] + EPSC);
      float o1 = hb0 + num[1] / (den[1] + EPSC);
      float o2 = hb0 + num[2] / (den[2] + EPSC);
      float o3 = hb0 + num[3] / (den[3] + EPSC);
      ws[QONLY_BASE + b * 3 + 0] = fabsf(o0 - o1);
      ws[QONLY_BASE + b * 3 + 1] = fabsf(o0 - o2);
      ws[QONLY_BASE + b * 3 + 2] = fabsf(o0 - o3);
    }
  }
}

__global__ __launch_bounds__(64) void finalize_kernel(const float* __restrict__ ws,
                                                      const float* __restrict__ sbp,
                                                      float* __restrict__ out)
{
  int lane = threadIdx.x;
  float s0 = 0.f, s1 = 0.f, s2 = 0.f, mv = 0.f, bv = 0.f;
  for (int i = lane; i < NBLK; i += 64) {
    s0 += ws[i];
    s1 += ws[1024 + i];
    s2 += ws[2048 + i];
    mv += ws[MAGS_BASE + 2 * i];
    bv += ws[MAGS_BASE + 2 * i + 1];
  }
#pragma unroll
  for (int off = 32; off >= 1; off >>= 1) {
    s0 += __shfl_xor(s0, off);
    s1 += __shfl_xor(s1, off);
    s2 += __shfl_xor(s2, off);
    mv += __shfl_xor(mv, off);
    bv += __shfl_xor(bv, off);
  }
  if (lane == 0) {
    float q0 = 0.f, q1 = 0.f, q2 = 0.f;
    for (int b = 0; b < B_; ++b) {
      q0 += ws[QONLY_BASE + b * 3 + 0];
      q1 += ws[QONLY_BASE + b * 3 + 1];
      q2 += ws[QONLY_BASE + b * 3 + 2];
    }
    float* oi = out + (size_t)B_ * T_ + (size_t)B_ * T_ * 8;
    const float inv_bt = 1.f / ((float)B_ * (float)T_);
    oi[0] = fabsf(1.f + sbp[0]);
    oi[1] = mv / ((float)B_ * (float)L_ * 4.f);
    oi[2] = bv / ((float)B_ * (float)L_ * 6.f);
    oi[3] = s0 * inv_bt;
    oi[4] = s1 * inv_bt;
    oi[5] = s2 * inv_bt;
    oi[6] = q0 / (float)B_;
    oi[7] = q1 / (float)B_;
    oi[8] = q2 / (float)B_;
  }
}

extern "C" void kernel_launch(void* const* d_in, const int* in_sizes, int n_in,
                              void* d_out, int out_size, void* d_ws, size_t ws_size,
                              hipStream_t stream) {
  (void)in_sizes; (void)n_in; (void)out_size; (void)ws_size;
  const float* x  = (const float*)d_in[0];
  const float* sb = (const float*)d_in[1];
  const float* vs = (const float*)d_in[2];
  const float* vb = (const float*)d_in[3];
  const float* bw = (const float*)d_in[4];
  const float* WQ = (const float*)d_in[5];
  const float* WK = (const float*)d_in[6];
  const float* WV = (const float*)d_in[7];
  const float* hW = (const float*)d_in[8];
  const float* hb = (const float*)d_in[9];
  float* out = (float*)d_out;
  float* ws  = (float*)d_ws;

  attn_kernel<<<dim3(NTB, B_), 256, 0, stream>>>(x, sb, vs, vb, bw, WQ, WK, WV, hW, hb, out, ws);
  finalize_kernel<<<1, 64, 0, stream>>>(ws, sb, out);
}

// Round 6
// 81.358 us; speedup vs baseline: 5.1493x; 2.3194x over previous
//
#include <hip/hip_runtime.h>

#define B_ 16
#define L_ 4096
#define H_ 128
#define DM 11
#define LB 8
#define T_ (L_-LB)            /* 4088 */
#define TT 64                 /* t per block, 1 per lane of each wave */
#define NTB (L_/TT)           /* 64 tiles */
#define NBLK (NTB*B_)         /* 1024 blocks */
#define EPSC 1e-6f
#define MAGS_BASE 4096
#define QONLY_BASE 8192

/* ws layout (floats):
   [0..3071]       attn |delta| partials, 3 variants x 1024 blocks
   [4096..6143]    mags partials, 1024 blocks x {vec,biv}
   [8192..8239]    qonly |delta|, 16 b x 3 variants
*/

__device__ __forceinline__ float phi_f(float a) { return fmaxf(a, 0.01f * a) + 1.f; }

__device__ __forceinline__ float4 phi4(float a, float b, float c, float d) {
  return make_float4(phi_f(a), phi_f(b), phi_f(c), phi_f(d));
}

/* r[0..3] = vector dims (M dims 1..4), r[4..9] = bivector dims (M dims 5..10) */
__device__ __forceinline__ void ga_parts(const float4 xv, const float* __restrict__ vs4,
                                         const float* __restrict__ vb4,
                                         const float* __restrict__ bw6, float* __restrict__ r) {
  r[0] = xv.x * vs4[0] + vb4[0];
  r[1] = xv.y * vs4[1] + vb4[1];
  r[2] = xv.z * vs4[2] + vb4[2];
  r[3] = xv.w * vs4[3] + vb4[3];
  r[4] = bw6[0] * (xv.x - xv.y);
  r[5] = bw6[1] * (xv.x - xv.z);
  r[6] = bw6[2] * (xv.x - xv.w);
  r[7] = bw6[3] * (xv.y - xv.z);
  r[8] = bw6[4] * (xv.y - xv.w);
  r[9] = bw6[5] * (xv.z - xv.w);
}

/* vec & biv partial dots against an 11-float weight row (w[0]=scalar, w[1..10]) */
__device__ __forceinline__ void dot2(const float* __restrict__ r, const float* __restrict__ w,
                                     float& dv, float& db) {
  dv = r[0] * w[1] + r[1] * w[2] + r[2] * w[3] + r[3] * w[4];
  db = r[4] * w[5] + r[5] * w[6] + r[6] * w[7] + r[7] * w[8] + r[8] * w[9] + r[9] * w[10];
}

__global__ __launch_bounds__(256) void attn_kernel(
    const float* __restrict__ x, const float* __restrict__ sbp,
    const float* __restrict__ vs, const float* __restrict__ vb,
    const float* __restrict__ bw, const float* __restrict__ WQ,
    const float* __restrict__ WK, const float* __restrict__ WV,
    const float* __restrict__ hW, const float* __restrict__ hb,
    float* __restrict__ out, float* __restrict__ ws)
{
  __shared__ float4 sK4[4][8][72];   /* [wave][hl][row] — h-major, conflict-free */
  __shared__ float4 sU4[72];
  __shared__ float  sWVe[16];

  const int tid  = threadIdx.x;
  const int lane = tid & 63;
  const int hq   = __builtin_amdgcn_readfirstlane(tid >> 6);  /* wave = h-quarter */
  const int tile = blockIdx.x;
  const int b    = blockIdx.y;
  const int base = tile * TT;

  const float sb0 = sbp[0];
  const float m0c = 1.f + sb0;
  float vs4[4] = {vs[0], vs[1], vs[2], vs[3]};
  float vb4[4] = {vb[0], vb[1], vb[2], vb[3]};
  float bw6[6] = {bw[0], bw[1], bw[2], bw[3], bw[4], bw[5]};
  const float hb0 = hb[0];

  const float4* xb = (const float4*)x + (size_t)b * L_;

  /* M rows in registers: staging row (lane), q row (lane+8), extra rows 64..71 (lanes 0..7) */
  float ms[10], mq[10], m2[10];
  ga_parts(xb[base + lane], vs4, vb4, bw6, ms);
  {
    int qp = base + lane + LB;
    if (qp < L_) ga_parts(xb[qp], vs4, vb4, bw6, mq);
    else { for (int i = 0; i < 10; ++i) mq[i] = 0.f; }
  }
  const bool has2 = (lane < LB);
  if (has2) {
    int p2 = base + 64 + lane;
    if (p2 < L_) ga_parts(xb[p2], vs4, vb4, bw6, m2);
    else { for (int i = 0; i < 10; ++i) m2[i] = 0.f; }
  }
  float magv = fabsf(ms[0]) + fabsf(ms[1]) + fabsf(ms[2]) + fabsf(ms[3]);
  float magb = fabsf(ms[4]) + fabsf(ms[5]) + fabsf(ms[6]) + fabsf(ms[7]) + fabsf(ms[8]) + fabsf(ms[9]);

  /* WVe by wave 1 */
  if (hq == 1 && lane < DM) {
    float a = 0.f;
    for (int g = 0; g < H_; ++g) a += WV[g * DM + lane] * hW[g];
    sWVe[lane] = a;
  }
  __syncthreads();   /* sWVe ready */

  /* wave 0 stages u4 (variant-packed u = M . WVe) */
  if (hq == 0) {
    float wv[11];
#pragma unroll
    for (int d = 0; d < DM; ++d) wv[d] = sWVe[d];
    float dv, db;
    dot2(ms, wv, dv, db);
    float c0 = m0c * wv[0];
    sU4[lane] = make_float4(c0 + dv + db, dv + db, c0 + db, c0 + dv);
    if (has2) {
      dot2(m2, wv, dv, db);
      sU4[64 + lane] = make_float4(c0 + dv + db, dv + db, c0 + db, c0 + dv);
    }
  }

  float4 s4[8];
#pragma unroll
  for (int l = 0; l < 8; ++l) s4[l] = make_float4(0.f, 0.f, 0.f, 0.f);

  const float* __restrict__ WKq = WK + (hq * 32) * DM;  /* uniform base */
  const float* __restrict__ WQq = WQ + (hq * 32) * DM;

#pragma unroll 1
  for (int c = 0; c < 4; ++c) {           /* 4 chunks of 8 h per wave */
#pragma unroll
    for (int hl = 0; hl < 8; ++hl) {
      const float* wk = WKq + (c * 8 + hl) * DM;   /* uniform -> s_load */
      float dv, db;
      dot2(ms, wk, dv, db);
      float c0 = m0c * wk[0];
      float t1 = dv + db;
      sK4[hq][hl][lane] = phi4(c0 + t1, t1, c0 + db, c0 + dv);
    }
    if (has2) {
#pragma unroll
      for (int hl = 0; hl < 8; ++hl) {
        const float* wk = WKq + (c * 8 + hl) * DM;
        float dv, db;
        dot2(m2, wk, dv, db);
        float c0 = m0c * wk[0];
        float t1 = dv + db;
        sK4[hq][hl][64 + lane] = phi4(c0 + t1, t1, c0 + db, c0 + dv);
      }
    }
    __syncthreads();
#pragma unroll
    for (int hl = 0; hl < 8; ++hl) {
      const float* wq = WQq + (c * 8 + hl) * DM;   /* uniform -> s_load */
      float dv, db;
      dot2(mq, wq, dv, db);
      float c0 = m0c * wq[0];
      float t1 = dv + db;
      float4 q4 = phi4(c0 + t1, t1, c0 + db, c0 + dv);
#pragma unroll
      for (int l = 0; l < 8; ++l) {
        float4 k4 = sK4[hq][hl][lane + l];
        s4[l].x += q4.x * k4.x;
        s4[l].y += q4.y * k4.y;
        s4[l].z += q4.z * k4.z;
        s4[l].w += q4.w * k4.w;
      }
    }
    __syncthreads();
  }

  /* cross-wave score reduce: reuse sK4 as scratch (swizzled slots) */
  float4* scr = &sK4[0][0][0];
  if (hq != 0) {
    int off = (hq - 1) * 512 + lane * 8;
#pragma unroll
    for (int l = 0; l < 8; ++l) scr[off + (l ^ (lane & 7))] = s4[l];
  }
  __syncthreads();

  if (hq == 0) {
#pragma unroll
    for (int j = 0; j < 3; ++j) {
      int off = j * 512 + lane * 8;
#pragma unroll
      for (int l = 0; l < 8; ++l) {
        float4 v = scr[off + (l ^ (lane & 7))];
        s4[l].x += v.x; s4[l].y += v.y; s4[l].z += v.z; s4[l].w += v.w;
      }
    }
    float den0 = EPSC, den1 = EPSC, den2 = EPSC, den3 = EPSC;
    float num0 = 0.f, num1 = 0.f, num2 = 0.f, num3 = 0.f;
#pragma unroll
    for (int l = 0; l < 8; ++l) {
      float4 u4 = sU4[lane + l];
      den0 += s4[l].x; num0 += s4[l].x * u4.x;
      den1 += s4[l].y; num1 += s4[l].y * u4.y;
      den2 += s4[l].z; num2 += s4[l].z * u4.z;
      den3 += s4[l].w; num3 += s4[l].w * u4.w;
    }
    float p0 = hb0 + num0 / den0;
    float p1 = hb0 + num1 / den1;
    float p2 = hb0 + num2 / den2;
    float p3 = hb0 + num3 / den3;

    const int t = base + lane;
    const bool tvalid = (t < T_);
    if (tvalid) {
      out[(size_t)b * T_ + t] = p0;
      float inv = 1.f / den0;
      float4* wp = (float4*)(out + (size_t)B_ * T_ + ((size_t)b * T_ + t) * 8);
      wp[0] = make_float4(s4[0].x * inv, s4[1].x * inv, s4[2].x * inv, s4[3].x * inv);
      wp[1] = make_float4(s4[4].x * inv, s4[5].x * inv, s4[6].x * inv, s4[7].x * inv);
    }
    float d1 = tvalid ? fabsf(p0 - p1) : 0.f;
    float d2 = tvalid ? fabsf(p0 - p2) : 0.f;
    float d3 = tvalid ? fabsf(p0 - p3) : 0.f;
#pragma unroll
    for (int off = 32; off >= 1; off >>= 1) {
      d1 += __shfl_xor(d1, off);
      d2 += __shfl_xor(d2, off);
      d3 += __shfl_xor(d3, off);
      magv += __shfl_xor(magv, off);
      magb += __shfl_xor(magb, off);
    }
    if (lane == 0) {
      int bid = b * NTB + tile;
      ws[bid]             = d1;
      ws[1024 + bid]      = d2;
      ws[2048 + bid]      = d3;
      ws[MAGS_BASE + 2 * bid]     = magv;
      ws[MAGS_BASE + 2 * bid + 1] = magb;
    }
  }

  /* qonly fused on wave 1 of the last tile (runs concurrent with wave 0 epilogue) */
  if (hq == 1 && tile == NTB - 1) {
    const int h0 = lane, h1 = lane + 64;
    float wq0[11], wq1[11], wk0[11], wk1[11], wv[11];
#pragma unroll
    for (int d = 0; d < DM; ++d) {
      wq0[d] = WQ[h0 * DM + d]; wq1[d] = WQ[h1 * DM + d];
      wk0[d] = WK[h0 * DM + d]; wk1[d] = WK[h1 * DM + d];
      wv[d]  = sWVe[d];
    }
    float A0 = 0.f, Z0 = 0.f, A1 = 0.f, Z1 = 0.f;
#pragma unroll
    for (int l = 0; l < LB; ++l) {
      float4 xv = xb[L_ - 1 - LB + l];
      float r[10];
      ga_parts(xv, vs4, vb4, bw6, r);
      float uv, ub;
      dot2(r, wv, uv, ub);
      float u = m0c * wv[0] + uv + ub;
      float dv, db;
      dot2(r, wk0, dv, db);
      float k0 = phi_f(m0c * wk0[0] + dv + db);
      dot2(r, wk1, dv, db);
      float k1 = phi_f(m0c * wk1[0] + dv + db);
      A0 += k0 * u; Z0 += k0;
      A1 += k1 * u; Z1 += k1;
    }
    float q0, q1;
    {
      float4 xv = xb[L_ - 1];
      float r[10];
      ga_parts(xv, vs4, vb4, bw6, r);
      float dv, db;
      dot2(r, wq0, dv, db);
      q0 = phi_f(m0c * wq0[0] + dv + db);
      dot2(r, wq1, dv, db);
      q1 = phi_f(m0c * wq1[0] + dv + db);
    }
    float i00 = fabsf(wq0[0]);
    float i01 = fabsf(wq0[1]) + fabsf(wq0[2]) + fabsf(wq0[3]) + fabsf(wq0[4]);
    float i02 = fabsf(wq0[5]) + fabsf(wq0[6]) + fabsf(wq0[7]) + fabsf(wq0[8]) + fabsf(wq0[9]) + fabsf(wq0[10]);
    float i10 = fabsf(wq1[0]);
    float i11 = fabsf(wq1[1]) + fabsf(wq1[2]) + fabsf(wq1[3]) + fabsf(wq1[4]);
    float i12 = fabsf(wq1[5]) + fabsf(wq1[6]) + fabsf(wq1[7]) + fabsf(wq1[8]) + fabsf(wq1[9]) + fabsf(wq1[10]);
    float mm0 = fmaxf(i00, i10), mm1 = fmaxf(i01, i11), mm2 = fmaxf(i02, i12);
#pragma unroll
    for (int off = 32; off >= 1; off >>= 1) {
      mm0 = fmaxf(mm0, __shfl_xor(mm0, off));
      mm1 = fmaxf(mm1, __shfl_xor(mm1, off));
      mm2 = fmaxf(mm2, __shfl_xor(mm2, off));
    }
    mm0 += 1e-12f; mm1 += 1e-12f; mm2 += 1e-12f;
    float qa[4], qb_[4];
    qa[0] = q0;                      qb_[0] = q1;
    qa[1] = q0 * (1.f - i00 / mm0);  qb_[1] = q1 * (1.f - i10 / mm0);
    qa[2] = q0 * (1.f - i01 / mm1);  qb_[2] = q1 * (1.f - i11 / mm1);
    qa[3] = q0 * (1.f - i02 / mm2);  qb_[3] = q1 * (1.f - i12 / mm2);
    float num[4], den[4];
#pragma unroll
    for (int cc = 0; cc < 4; ++cc) {
      num[cc] = qa[cc] * A0 + qb_[cc] * A1;
      den[cc] = qa[cc] * Z0 + qb_[cc] * Z1;
    }
#pragma unroll
    for (int off = 32; off >= 1; off >>= 1) {
#pragma unroll
      for (int cc = 0; cc < 4; ++cc) {
        num[cc] += __shfl_xor(num[cc], off);
        den[cc] += __shfl_xor(den[cc], off);
      }
    }
    if (lane == 0) {
      float o0 = hb0 + num[0] / (den[0] + EPSC);
      float o1 = hb0 + num[1] / (den[1] + EPSC);
      float o2 = hb0 + num[2] / (den[2] + EPSC);
      float o3 = hb0 + num[3] / (den[3] + EPSC);
      ws[QONLY_BASE + b * 3 + 0] = fabsf(o0 - o1);
      ws[QONLY_BASE + b * 3 + 1] = fabsf(o0 - o2);
      ws[QONLY_BASE + b * 3 + 2] = fabsf(o0 - o3);
    }
  }
}

__global__ __launch_bounds__(64) void finalize_kernel(const float* __restrict__ ws,
                                                      const float* __restrict__ sbp,
                                                      float* __restrict__ out)
{
  int lane = threadIdx.x;
  float s0 = 0.f, s1 = 0.f, s2 = 0.f, mv = 0.f, bv = 0.f;
  for (int i = lane; i < NBLK; i += 64) {
    s0 += ws[i];
    s1 += ws[1024 + i];
    s2 += ws[2048 + i];
    mv += ws[MAGS_BASE + 2 * i];
    bv += ws[MAGS_BASE + 2 * i + 1];
  }
#pragma unroll
  for (int off = 32; off >= 1; off >>= 1) {
    s0 += __shfl_xor(s0, off);
    s1 += __shfl_xor(s1, off);
    s2 += __shfl_xor(s2, off);
    mv += __shfl_xor(mv, off);
    bv += __shfl_xor(bv, off);
  }
  if (lane == 0) {
    float q0 = 0.f, q1 = 0.f, q2 = 0.f;
    for (int b = 0; b < B_; ++b) {
      q0 += ws[QONLY_BASE + b * 3 + 0];
      q1 += ws[QONLY_BASE + b * 3 + 1];
      q2 += ws[QONLY_BASE + b * 3 + 2];
    }
    float* oi = out + (size_t)B_ * T_ + (size_t)B_ * T_ * 8;
    const float inv_bt = 1.f / ((float)B_ * (float)T_);
    oi[0] = fabsf(1.f + sbp[0]);
    oi[1] = mv / ((float)B_ * (float)L_ * 4.f);
    oi[2] = bv / ((float)B_ * (float)L_ * 6.f);
    oi[3] = s0 * inv_bt;
    oi[4] = s1 * inv_bt;
    oi[5] = s2 * inv_bt;
    oi[6] = q0 / (float)B_;
    oi[7] = q1 / (float)B_;
    oi[8] = q2 / (float)B_;
  }
}

extern "C" void kernel_launch(void* const* d_in, const int* in_sizes, int n_in,
                              void* d_out, int out_size, void* d_ws, size_t ws_size,
                              hipStream_t stream) {
  (void)in_sizes; (void)n_in; (void)out_size; (void)ws_size;
  const float* x  = (const float*)d_in[0];
  const float* sb = (const float*)d_in[1];
  const float* vs = (const float*)d_in[2];
  const float* vb = (const float*)d_in[3];
  const float* bw = (const float*)d_in[4];
  const float* WQ = (const float*)d_in[5];
  const float* WK = (const float*)d_in[6];
  const float* WV = (const float*)d_in[7];
  const float* hW = (const float*)d_in[8];
  const float* hb = (const float*)d_in[9];
  float* out = (float*)d_out;
  float* ws  = (float*)d_ws;

  attn_kernel<<<dim3(NTB, B_), 256, 0, stream>>>(x, sb, vs, vb, bw, WQ, WK, WV, hW, hb, out, ws);
  finalize_kernel<<<1, 64, 0, stream>>>(ws, sb, out);
}

// Round 7
// 80.501 us; speedup vs baseline: 5.2042x; 1.0106x over previous
//
#include <hip/hip_runtime.h>

#define B_ 16
#define L_ 4096
#define H_ 128
#define DM 11
#define LB 8
#define T_ (L_-LB)            /* 4088 */
#define TT 64                 /* t per block, 1 per lane of each wave */
#define NTB (L_/TT)           /* 64 tiles */
#define NBLK (NTB*B_)         /* 1024 blocks */
#define EPSC 1e-6f
#define MAGS_BASE 4096
#define QONLY_BASE 8192

/* ws layout (floats):
   [0..3071]       attn |delta| partials, 3 variants x 1024 blocks
   [4096..6143]    mags partials, 1024 blocks x {vec,biv}
   [8192..8239]    qonly |delta|, 16 b x 3 variants
*/

__device__ __forceinline__ float phi_f(float a) { return fmaxf(a, 0.01f * a) + 1.f; }

__device__ __forceinline__ float4 phi4(float a, float b, float c, float d) {
  return make_float4(phi_f(a), phi_f(b), phi_f(c), phi_f(d));
}

/* r[0..3] = vector dims (M dims 1..4), r[4..9] = bivector dims (M dims 5..10) */
__device__ __forceinline__ void ga_parts(const float4 xv, const float* __restrict__ vs4,
                                         const float* __restrict__ vb4,
                                         const float* __restrict__ bw6, float* __restrict__ r) {
  r[0] = xv.x * vs4[0] + vb4[0];
  r[1] = xv.y * vs4[1] + vb4[1];
  r[2] = xv.z * vs4[2] + vb4[2];
  r[3] = xv.w * vs4[3] + vb4[3];
  r[4] = bw6[0] * (xv.x - xv.y);
  r[5] = bw6[1] * (xv.x - xv.z);
  r[6] = bw6[2] * (xv.x - xv.w);
  r[7] = bw6[3] * (xv.y - xv.z);
  r[8] = bw6[4] * (xv.y - xv.w);
  r[9] = bw6[5] * (xv.z - xv.w);
}

/* vec & biv partial dots against an 11-float weight row (w[0]=scalar, w[1..10]) */
__device__ __forceinline__ void dot2(const float* __restrict__ r, const float* __restrict__ w,
                                     float& dv, float& db) {
  dv = r[0] * w[1] + r[1] * w[2] + r[2] * w[3] + r[3] * w[4];
  db = r[4] * w[5] + r[5] * w[6] + r[6] * w[7] + r[7] * w[8] + r[8] * w[9] + r[9] * w[10];
}

__global__ __launch_bounds__(256) void attn_kernel(
    const float* __restrict__ x, const float* __restrict__ sbp,
    const float* __restrict__ vs, const float* __restrict__ vb,
    const float* __restrict__ bw, const float* __restrict__ WQ,
    const float* __restrict__ WK, const float* __restrict__ WV,
    const float* __restrict__ hW, const float* __restrict__ hb,
    float* __restrict__ out, float* __restrict__ ws)
{
  __shared__ float4 sK4[4][8][72];   /* [wave][hl][row] — h-major, wave-private */
  __shared__ float4 sU4[72];
  __shared__ float  sWVe[16];

  const int tid  = threadIdx.x;
  const int lane = tid & 63;
  const int hq   = __builtin_amdgcn_readfirstlane(tid >> 6);  /* wave = h-quarter */
  const int tile = blockIdx.x;
  const int b    = blockIdx.y;
  const int base = tile * TT;

  const float sb0 = sbp[0];
  const float m0c = 1.f + sb0;
  float vs4[4] = {vs[0], vs[1], vs[2], vs[3]};
  float vb4[4] = {vb[0], vb[1], vb[2], vb[3]};
  float bw6[6] = {bw[0], bw[1], bw[2], bw[3], bw[4], bw[5]};
  const float hb0 = hb[0];

  const float4* xb = (const float4*)x + (size_t)b * L_;

  /* M rows in registers: staging row (lane) and q row (lane+8).
     Rows 64..71 are exactly mq of lanes 56..63 — no third array needed. */
  float ms[10], mq[10];
  ga_parts(xb[base + lane], vs4, vb4, bw6, ms);
  {
    int qp = base + lane + LB;
    if (qp < L_) ga_parts(xb[qp], vs4, vb4, bw6, mq);
    else { for (int i = 0; i < 10; ++i) mq[i] = 0.f; }
  }
  const bool hiLane = (lane >= 56);
  float magv = fabsf(ms[0]) + fabsf(ms[1]) + fabsf(ms[2]) + fabsf(ms[3]);
  float magb = fabsf(ms[4]) + fabsf(ms[5]) + fabsf(ms[6]) + fabsf(ms[7]) + fabsf(ms[8]) + fabsf(ms[9]);

  /* WVe by wave 1 */
  if (hq == 1 && lane < DM) {
    float a = 0.f;
    for (int g = 0; g < H_; ++g) a += WV[g * DM + lane] * hW[g];
    sWVe[lane] = a;
  }
  __syncthreads();   /* barrier #1: sWVe ready */

  /* wave 0 stages u4 (variant-packed u = M . WVe); rows 64..71 via mq of lanes 56..63 */
  if (hq == 0) {
    float wv[11];
#pragma unroll
    for (int d = 0; d < DM; ++d) wv[d] = sWVe[d];
    float dv, db;
    dot2(ms, wv, dv, db);
    float c0 = m0c * wv[0];
    sU4[lane] = make_float4(c0 + dv + db, dv + db, c0 + db, c0 + dv);
    if (hiLane) {
      dot2(mq, wv, dv, db);
      sU4[lane + 8] = make_float4(c0 + dv + db, dv + db, c0 + db, c0 + dv);
    }
  }

  float4 s4[8];
#pragma unroll
  for (int l = 0; l < 8; ++l) s4[l] = make_float4(0.f, 0.f, 0.f, 0.f);

  const float* __restrict__ WKq = WK + (hq * 32) * DM;  /* uniform base */
  const float* __restrict__ WQq = WQ + (hq * 32) * DM;

  /* main loop: NO block barriers — sK4[hq] is wave-private; compiler-inserted
     lgkmcnt waits order same-wave ds_write -> ds_read. */
#pragma unroll 1
  for (int c = 0; c < 4; ++c) {           /* 4 chunks of 8 h per wave */
#pragma unroll
    for (int hl = 0; hl < 8; ++hl) {
      const float* wk = WKq + (c * 8 + hl) * DM;   /* uniform -> s_load */
      float dv, db;
      dot2(ms, wk, dv, db);
      float c0 = m0c * wk[0];
      float t1 = dv + db;
      sK4[hq][hl][lane] = phi4(c0 + t1, t1, c0 + db, c0 + dv);
      if (hiLane) {                        /* rows 64..71 from mq */
        float dv2, db2;
        dot2(mq, wk, dv2, db2);
        float t2 = dv2 + db2;
        sK4[hq][hl][lane + 8] = phi4(c0 + t2, t2, c0 + db2, c0 + dv2);
      }
    }
#pragma unroll
    for (int hl = 0; hl < 8; ++hl) {
      const float* wq = WQq + (c * 8 + hl) * DM;   /* uniform -> s_load */
      float dv, db;
      dot2(mq, wq, dv, db);
      float c0 = m0c * wq[0];
      float t1 = dv + db;
      float4 q4 = phi4(c0 + t1, t1, c0 + db, c0 + dv);
#pragma unroll
      for (int l = 0; l < 8; ++l) {
        float4 k4 = sK4[hq][hl][lane + l];
        s4[l].x += q4.x * k4.x;
        s4[l].y += q4.y * k4.y;
        s4[l].z += q4.z * k4.z;
        s4[l].w += q4.w * k4.w;
      }
    }
  }

  /* cross-wave score reduce: reuse sK4 as scratch (swizzled slots) */
  __syncthreads();   /* barrier #2: everyone done with sK4 as K store */
  float4* scr = &sK4[0][0][0];
  if (hq != 0) {
    int off = (hq - 1) * 512 + lane * 8;
#pragma unroll
    for (int l = 0; l < 8; ++l) scr[off + (l ^ (lane & 7))] = s4[l];
  }
  __syncthreads();   /* barrier #3: partials visible */

  if (hq == 0) {
#pragma unroll
    for (int j = 0; j < 3; ++j) {
      int off = j * 512 + lane * 8;
#pragma unroll
      for (int l = 0; l < 8; ++l) {
        float4 v = scr[off + (l ^ (lane & 7))];
        s4[l].x += v.x; s4[l].y += v.y; s4[l].z += v.z; s4[l].w += v.w;
      }
    }
    float den0 = EPSC, den1 = EPSC, den2 = EPSC, den3 = EPSC;
    float num0 = 0.f, num1 = 0.f, num2 = 0.f, num3 = 0.f;
#pragma unroll
    for (int l = 0; l < 8; ++l) {
      float4 u4 = sU4[lane + l];
      den0 += s4[l].x; num0 += s4[l].x * u4.x;
      den1 += s4[l].y; num1 += s4[l].y * u4.y;
      den2 += s4[l].z; num2 += s4[l].z * u4.z;
      den3 += s4[l].w; num3 += s4[l].w * u4.w;
    }
    float p0 = hb0 + num0 / den0;
    float p1 = hb0 + num1 / den1;
    float p2 = hb0 + num2 / den2;
    float p3 = hb0 + num3 / den3;

    const int t = base + lane;
    const bool tvalid = (t < T_);
    if (tvalid) {
      out[(size_t)b * T_ + t] = p0;
      float inv = 1.f / den0;
      float4* wp = (float4*)(out + (size_t)B_ * T_ + ((size_t)b * T_ + t) * 8);
      wp[0] = make_float4(s4[0].x * inv, s4[1].x * inv, s4[2].x * inv, s4[3].x * inv);
      wp[1] = make_float4(s4[4].x * inv, s4[5].x * inv, s4[6].x * inv, s4[7].x * inv);
    }
    float d1 = tvalid ? fabsf(p0 - p1) : 0.f;
    float d2 = tvalid ? fabsf(p0 - p2) : 0.f;
    float d3 = tvalid ? fabsf(p0 - p3) : 0.f;
#pragma unroll
    for (int off = 32; off >= 1; off >>= 1) {
      d1 += __shfl_xor(d1, off);
      d2 += __shfl_xor(d2, off);
      d3 += __shfl_xor(d3, off);
      magv += __shfl_xor(magv, off);
      magb += __shfl_xor(magb, off);
    }
    if (lane == 0) {
      int bid = b * NTB + tile;
      ws[bid]             = d1;
      ws[1024 + bid]      = d2;
      ws[2048 + bid]      = d3;
      ws[MAGS_BASE + 2 * bid]     = magv;
      ws[MAGS_BASE + 2 * bid + 1] = magb;
    }
  }

  /* qonly fused on wave 1 of the last tile (runs concurrent with wave 0 epilogue) */
  if (hq == 1 && tile == NTB - 1) {
    const int h0 = lane, h1 = lane + 64;
    float wq0[11], wq1[11], wk0[11], wk1[11], wv[11];
#pragma unroll
    for (int d = 0; d < DM; ++d) {
      wq0[d] = WQ[h0 * DM + d]; wq1[d] = WQ[h1 * DM + d];
      wk0[d] = WK[h0 * DM + d]; wk1[d] = WK[h1 * DM + d];
      wv[d]  = sWVe[d];
    }
    float A0 = 0.f, Z0 = 0.f, A1 = 0.f, Z1 = 0.f;
#pragma unroll
    for (int l = 0; l < LB; ++l) {
      float4 xv = xb[L_ - 1 - LB + l];
      float r[10];
      ga_parts(xv, vs4, vb4, bw6, r);
      float uv, ub;
      dot2(r, wv, uv, ub);
      float u = m0c * wv[0] + uv + ub;
      float dv, db;
      dot2(r, wk0, dv, db);
      float k0 = phi_f(m0c * wk0[0] + dv + db);
      dot2(r, wk1, dv, db);
      float k1 = phi_f(m0c * wk1[0] + dv + db);
      A0 += k0 * u; Z0 += k0;
      A1 += k1 * u; Z1 += k1;
    }
    float q0, q1;
    {
      float4 xv = xb[L_ - 1];
      float r[10];
      ga_parts(xv, vs4, vb4, bw6, r);
      float dv, db;
      dot2(r, wq0, dv, db);
      q0 = phi_f(m0c * wq0[0] + dv + db);
      dot2(r, wq1, dv, db);
      q1 = phi_f(m0c * wq1[0] + dv + db);
    }
    float i00 = fabsf(wq0[0]);
    float i01 = fabsf(wq0[1]) + fabsf(wq0[2]) + fabsf(wq0[3]) + fabsf(wq0[4]);
    float i02 = fabsf(wq0[5]) + fabsf(wq0[6]) + fabsf(wq0[7]) + fabsf(wq0[8]) + fabsf(wq0[9]) + fabsf(wq0[10]);
    float i10 = fabsf(wq1[0]);
    float i11 = fabsf(wq1[1]) + fabsf(wq1[2]) + fabsf(wq1[3]) + fabsf(wq1[4]);
    float i12 = fabsf(wq1[5]) + fabsf(wq1[6]) + fabsf(wq1[7]) + fabsf(wq1[8]) + fabsf(wq1[9]) + fabsf(wq1[10]);
    float mm0 = fmaxf(i00, i10), mm1 = fmaxf(i01, i11), mm2 = fmaxf(i02, i12);
#pragma unroll
    for (int off = 32; off >= 1; off >>= 1) {
      mm0 = fmaxf(mm0, __shfl_xor(mm0, off));
      mm1 = fmaxf(mm1, __shfl_xor(mm1, off));
      mm2 = fmaxf(mm2, __shfl_xor(mm2, off));
    }
    mm0 += 1e-12f; mm1 += 1e-12f; mm2 += 1e-12f;
    float qa[4], qb_[4];
    qa[0] = q0;                      qb_[0] = q1;
    qa[1] = q0 * (1.f - i00 / mm0);  qb_[1] = q1 * (1.f - i10 / mm0);
    qa[2] = q0 * (1.f - i01 / mm1);  qb_[2] = q1 * (1.f - i11 / mm1);
    qa[3] = q0 * (1.f - i02 / mm2);  qb_[3] = q1 * (1.f - i12 / mm2);
    float num[4], den[4];
#pragma unroll
    for (int cc = 0; cc < 4; ++cc) {
      num[cc] = qa[cc] * A0 + qb_[cc] * A1;
      den[cc] = qa[cc] * Z0 + qb_[cc] * Z1;
    }
#pragma unroll
    for (int off = 32; off >= 1; off >>= 1) {
#pragma unroll
      for (int cc = 0; cc < 4; ++cc) {
        num[cc] += __shfl_xor(num[cc], off);
        den[cc] += __shfl_xor(den[cc], off);
      }
    }
    if (lane == 0) {
      float o0 = hb0 + num[0] / (den[0] + EPSC);
      float o1 = hb0 + num[1] / (den[1] + EPSC);
      float o2 = hb0 + num[2] / (den[2] + EPSC);
      float o3 = hb0 + num[3] / (den[3] + EPSC);
      ws[QONLY_BASE + b * 3 + 0] = fabsf(o0 - o1);
      ws[QONLY_BASE + b * 3 + 1] = fabsf(o0 - o2);
      ws[QONLY_BASE + b * 3 + 2] = fabsf(o0 - o3);
    }
  }
}

__global__ __launch_bounds__(64) void finalize_kernel(const float* __restrict__ ws,
                                                      const float* __restrict__ sbp,
                                                      float* __restrict__ out)
{
  int lane = threadIdx.x;
  float s0 = 0.f, s1 = 0.f, s2 = 0.f, mv = 0.f, bv = 0.f;
  for (int i = lane; i < NBLK; i += 64) {
    s0 += ws[i];
    s1 += ws[1024 + i];
    s2 += ws[2048 + i];
    mv += ws[MAGS_BASE + 2 * i];
    bv += ws[MAGS_BASE + 2 * i + 1];
  }
#pragma unroll
  for (int off = 32; off >= 1; off >>= 1) {
    s0 += __shfl_xor(s0, off);
    s1 += __shfl_xor(s1, off);
    s2 += __shfl_xor(s2, off);
    mv += __shfl_xor(mv, off);
    bv += __shfl_xor(bv, off);
  }
  if (lane == 0) {
    float q0 = 0.f, q1 = 0.f, q2 = 0.f;
    for (int b = 0; b < B_; ++b) {
      q0 += ws[QONLY_BASE + b * 3 + 0];
      q1 += ws[QONLY_BASE + b * 3 + 1];
      q2 += ws[QONLY_BASE + b * 3 + 2];
    }
    float* oi = out + (size_t)B_ * T_ + (size_t)B_ * T_ * 8;
    const float inv_bt = 1.f / ((float)B_ * (float)T_);
    oi[0] = fabsf(1.f + sbp[0]);
    oi[1] = mv / ((float)B_ * (float)L_ * 4.f);
    oi[2] = bv / ((float)B_ * (float)L_ * 6.f);
    oi[3] = s0 * inv_bt;
    oi[4] = s1 * inv_bt;
    oi[5] = s2 * inv_bt;
    oi[6] = q0 / (float)B_;
    oi[7] = q1 / (float)B_;
    oi[8] = q2 / (float)B_;
  }
}

extern "C" void kernel_launch(void* const* d_in, const int* in_sizes, int n_in,
                              void* d_out, int out_size, void* d_ws, size_t ws_size,
                              hipStream_t stream) {
  (void)in_sizes; (void)n_in; (void)out_size; (void)ws_size;
  const float* x  = (const float*)d_in[0];
  const float* sb = (const float*)d_in[1];
  const float* vs = (const float*)d_in[2];
  const float* vb = (const float*)d_in[3];
  const float* bw = (const float*)d_in[4];
  const float* WQ = (const float*)d_in[5];
  const float* WK = (const float*)d_in[6];
  const float* WV = (const float*)d_in[7];
  const float* hW = (const float*)d_in[8];
  const float* hb = (const float*)d_in[9];
  float* out = (float*)d_out;
  float* ws  = (float*)d_ws;

  attn_kernel<<<dim3(NTB, B_), 256, 0, stream>>>(x, sb, vs, vb, bw, WQ, WK, WV, hW, hb, out, ws);
  finalize_kernel<<<1, 64, 0, stream>>>(ws, sb, out);
}